// Round 1
// baseline (634.660 us; speedup 1.0000x reference)
//
#include <hip/hip_runtime.h>

#define NBATCH 4096
#define M 64
#define HID 128
#define AOUT 64

__device__ __forceinline__ float4 ld4(const float* p) { return *(const float4*)p; }
__device__ __forceinline__ void st4(float* p, float4 v) { *(float4*)p = v; }
__device__ __forceinline__ float lrelu(float x) { return x > 0.0f ? x : 0.2f * x; }
__device__ __forceinline__ float elu1(float x) { return x > 0.0f ? x : __expf(x) - 1.0f; }

// rotated LDS layout: element (i,k) lives at i*128 + ((k + 4*i) & 127)
__device__ __forceinline__ int rotidx(int i, int k) { return i * HID + ((k + 4 * i) & 127); }

__global__ __launch_bounds__(256)
void gat_kernel(const float* __restrict__ users,
                const float* __restrict__ W1,
                const float* __restrict__ a1,
                const float* __restrict__ W2,
                const float* __restrict__ a2,
                const float* __restrict__ mw1,
                const float* __restrict__ mb1,
                const float* __restrict__ mw2,
                const float* __restrict__ mb2,
                float* __restrict__ out)
{
    const int b = blockIdx.x;
    const int t = threadIdx.x;

    __shared__ float bigA[M * HID];      // 32 KB: Wh1 -> h1 -> Wh2 -> h2 (rotated layout)
    __shared__ float sW2t[16 * HID];     // 8 KB W2 staging (16 rows per chunk)
    __shared__ float sU[M * 3];
    __shared__ float sW1[3 * HID];
    __shared__ float sA1[2 * HID];
    __shared__ float sA2[2 * HID];
    __shared__ float sSi[M], sSj[M], sMi[M], sInvL[M];
    __shared__ float sPool[HID];
    __shared__ float sHid[32];
    __shared__ float sRaw[HID];
    __shared__ float sSums[2];

    // ---- Phase A: load small inputs ----
    if (t < 192) sU[t] = users[b * 192 + t];
    sA1[t] = a1[t];
    sA2[t] = a2[t];
    sW1[t] = W1[t];                 // t in [0,256) -> first 256 of 384
    if (t < 128) sW1[256 + t] = W1[256 + t];
    __syncthreads();

    // ---- Phase B: Wh1 = users @ W1  (64x3 @ 3x128) ----
    {
        const int k = t & 127;
        const int half = t >> 7;
        const float w0 = sW1[k], w1 = sW1[HID + k], w2 = sW1[2 * HID + k];
        #pragma unroll 8
        for (int ii = 0; ii < 32; ++ii) {
            const int i = ii * 2 + half;
            const float v = sU[i * 3] * w0 + sU[i * 3 + 1] * w1 + sU[i * 3 + 2] * w2;
            bigA[rotidx(i, k)] = v;
        }
    }
    __syncthreads();

    // ---- Two GAT layers ----
    for (int L = 0; L < 2; ++L) {
        if (L == 1) {
            // ---- Phase F: Wh2 = h1 @ W2 (64x128 @ 128x128), compute into regs, overwrite bigA ----
            const int kt = t & 31;   // k-tile: 4 cols kt*4..+3
            const int it = t >> 5;   // i-tile: 8 rows it*8..+7
            float acc[8][4];
            #pragma unroll
            for (int r = 0; r < 8; ++r) { acc[r][0] = acc[r][1] = acc[r][2] = acc[r][3] = 0.0f; }

            for (int ch = 0; ch < 8; ++ch) {
                __syncthreads();   // protect sW2t from previous chunk's readers
                {
                    const float* src = W2 + ch * 2048;
                    st4(&sW2t[t * 8], ld4(&src[t * 8]));
                    st4(&sW2t[t * 8 + 4], ld4(&src[t * 8 + 4]));
                }
                __syncthreads();
                #pragma unroll
                for (int cc = 0; cc < 16; cc += 4) {
                    const int c = ch * 16 + cc;
                    float h4[8][4];
                    #pragma unroll
                    for (int r = 0; r < 8; ++r) {
                        const int i = it * 8 + r;
                        float4 hv = ld4(&bigA[i * HID + ((c + 4 * i) & 127)]);
                        h4[r][0] = hv.x; h4[r][1] = hv.y; h4[r][2] = hv.z; h4[r][3] = hv.w;
                    }
                    float w4[4][4];
                    #pragma unroll
                    for (int d = 0; d < 4; ++d) {
                        float4 wv = ld4(&sW2t[(cc + d) * HID + kt * 4]);
                        w4[d][0] = wv.x; w4[d][1] = wv.y; w4[d][2] = wv.z; w4[d][3] = wv.w;
                    }
                    #pragma unroll
                    for (int r = 0; r < 8; ++r) {
                        #pragma unroll
                        for (int d = 0; d < 4; ++d) {
                            const float hh = h4[r][d];
                            acc[r][0] += hh * w4[d][0];
                            acc[r][1] += hh * w4[d][1];
                            acc[r][2] += hh * w4[d][2];
                            acc[r][3] += hh * w4[d][3];
                        }
                    }
                }
            }
            __syncthreads();   // all reads of h1 done
            #pragma unroll
            for (int r = 0; r < 8; ++r) {
                const int i = it * 8 + r;
                float4 v; v.x = acc[r][0]; v.y = acc[r][1]; v.z = acc[r][2]; v.w = acc[r][3];
                st4(&bigA[i * HID + ((kt * 4 + 4 * i) & 127)], v);
            }
            __syncthreads();
        }

        // ---- Phase C: si = Wh @ a[:128], sj = Wh @ a[128:] ----
        {
            const float* av = (L == 0) ? sA1 : sA2;
            if (t < 128) {
                const int row = t & 63;
                const float* ap = av + (t >> 6) * HID;
                float s = 0.0f;
                #pragma unroll 8
                for (int c = 0; c < HID; ++c)
                    s += bigA[row * HID + ((c + 4 * row) & 127)] * ap[c];
                if (t < 64) sSi[row] = s; else sSj[row] = s;
            }
        }
        __syncthreads();

        // ---- Phase D: per-row softmax stats (max, 1/sum) ----
        if (t < 64) {
            const float si = sSi[t];
            float m = -1e30f;
            for (int j = 0; j < 64; ++j) {
                const float e = lrelu(si + sSj[j]);
                m = fmaxf(m, e);
            }
            float l = 0.0f;
            for (int j = 0; j < 64; ++j) {
                const float e = lrelu(si + sSj[j]);
                l += __expf(e - m);
            }
            sMi[t] = m;
            sInvL[t] = 1.0f / l;
        }
        __syncthreads();

        // ---- Phase E: h = elu(attn @ Wh), compute into regs, overwrite bigA ----
        {
            const int i = t >> 2;   // row
            const int q = t & 3;    // k-partition: logical cols q*32 .. q*32+31
            const float si = sSi[i], mi = sMi[i], inv = sInvL[i];
            float acc[8][4];
            #pragma unroll
            for (int m8 = 0; m8 < 8; ++m8) { acc[m8][0] = acc[m8][1] = acc[m8][2] = acc[m8][3] = 0.0f; }

            #pragma unroll 4
            for (int j = 0; j < 64; ++j) {
                float e = lrelu(si + sSj[j]);
                const float aij = __expf(e - mi) * inv;
                #pragma unroll
                for (int m8 = 0; m8 < 8; ++m8) {
                    const int mm = m8 ^ q;   // XOR swizzle: q-partitions hit distinct bank groups
                    float4 wv = ld4(&bigA[j * HID + ((q * 32 + mm * 4 + 4 * j) & 127)]);
                    acc[m8][0] += aij * wv.x;
                    acc[m8][1] += aij * wv.y;
                    acc[m8][2] += aij * wv.z;
                    acc[m8][3] += aij * wv.w;
                }
            }
            __syncthreads();   // all reads of Wh done
            #pragma unroll
            for (int m8 = 0; m8 < 8; ++m8) {
                const int mm = m8 ^ q;
                float4 v;
                v.x = elu1(acc[m8][0]); v.y = elu1(acc[m8][1]);
                v.z = elu1(acc[m8][2]); v.w = elu1(acc[m8][3]);
                st4(&bigA[i * HID + ((q * 32 + mm * 4 + 4 * i) & 127)], v);
            }
            __syncthreads();
        }
    }

    // ---- Phase P: pooled[k] = max_i h2[i][k] ----
    if (t < 128) {
        float m = -1e30f;
        #pragma unroll 8
        for (int i = 0; i < 64; ++i)
            m = fmaxf(m, bigA[i * HID + ((t + 4 * i) & 127)]);
        sPool[t] = m;
    }
    __syncthreads();

    // ---- Phase R: readout MLP ----
    if (t < 32) {
        float s = mb1[t];
        #pragma unroll 8
        for (int c = 0; c < HID; ++c)
            s += sPool[c] * mw1[c * 32 + t];
        sHid[t] = fmaxf(s, 0.0f);
    }
    __syncthreads();
    if (t < 128) {
        float s = mb2[t];
        #pragma unroll 8
        for (int qq = 0; qq < 32; ++qq)
            s += sHid[qq] * mw2[qq * HID + t];
        sRaw[t] = fmaxf(s, 0.0f) + 1e-6f;
    }
    __syncthreads();
    if (t < 128) {
        float v = sRaw[t];
        #pragma unroll
        for (int off = 32; off > 0; off >>= 1)
            v += __shfl_down(v, off, 64);
        if ((t & 63) == 0) sSums[t >> 6] = v;
    }
    __syncthreads();
    if (t < 64) {
        const float sumD = sSums[0] + 1e-6f;   // raw_delta = readout[:, :64]
        const float sumP = sSums[1] + 1e-6f;   // raw_power = readout[:, 64:]
        const float dlt = 98.425f * sRaw[t] / sumD;        // Bmax = 2*50 - 63*0.025
        const float pwr = 1.0f * sRaw[64 + t] / sumP;      // PMAX = 1.0
        out[b * 64 + t] = pwr;                              // output 0: power
        out[NBATCH * 64 + b * 64 + t] = dlt;                // output 1: delta
    }
}

extern "C" void kernel_launch(void* const* d_in, const int* in_sizes, int n_in,
                              void* d_out, int out_size, void* d_ws, size_t ws_size,
                              hipStream_t stream) {
    const float* users = (const float*)d_in[0];
    const float* W1    = (const float*)d_in[1];
    const float* a1    = (const float*)d_in[2];
    const float* W2    = (const float*)d_in[3];
    const float* a2    = (const float*)d_in[4];
    const float* mw1   = (const float*)d_in[5];
    const float* mb1   = (const float*)d_in[6];
    const float* mw2   = (const float*)d_in[7];
    const float* mb2   = (const float*)d_in[8];
    float* out = (float*)d_out;

    gat_kernel<<<NBATCH, 256, 0, stream>>>(users, W1, a1, W2, a2, mw1, mb1, mw2, mb2, out);
}

// Round 3
// 200.284 us; speedup vs baseline: 3.1688x; 3.1688x over previous
//
#include <hip/hip_runtime.h>

#define NBATCH 4096

typedef _Float16 f16;
typedef __attribute__((ext_vector_type(8))) _Float16 f16x8;
typedef __attribute__((ext_vector_type(4))) _Float16 f16x4;
typedef __attribute__((ext_vector_type(4))) float f32x4;

__device__ __forceinline__ float lrelu(float x) { return x > 0.0f ? x : 0.2f * x; }
__device__ __forceinline__ float elu1(float x)  { return x > 0.0f ? x : __expf(x) - 1.0f; }

// XOR-swizzled LDS layouts; every 8-element (16 B) group is 16B-aligned.
__device__ __forceinline__ int idxWh(int f, int n) { return f * 64  + (((n >> 3) ^ (f & 7))  << 3) + (n & 7); } // WhT[feat][node] 128x64
__device__ __forceinline__ int idxH (int n, int f) { return n * 128 + (((f >> 3) ^ (n & 15)) << 3) + (f & 7); } // h1[node][feat]  64x128
__device__ __forceinline__ int idxP (int i, int j) { return i * 64  + (((j >> 3) ^ (i & 7))  << 3) + (j & 7); } // P[i][j]         64x64
__device__ __forceinline__ int idxW (int nl,int k) { return nl * 128 + (((k >> 3) ^ (nl & 15)) << 3) + (k & 7); } // W2 stage 64x128

// W2 (128x128 f32 row-major) -> W2^T f16: w2t[n][k] = W2[k][n]
__global__ void w2t_prep(const float* __restrict__ W2, f16* __restrict__ w2t) {
    int idx = blockIdx.x * 256 + threadIdx.x;     // 16384
    int k = idx >> 7, n = idx & 127;              // coalesced read
    w2t[n * 128 + k] = (f16)W2[k * 128 + n];
}

__global__ __launch_bounds__(256)
void gat_kernel(const float* __restrict__ users,
                const float* __restrict__ W1,
                const float* __restrict__ a1,
                const float* __restrict__ a2,
                const f16* __restrict__ w2t,
                const float* __restrict__ mw1,
                const float* __restrict__ mb1,
                const float* __restrict__ mw2,
                const float* __restrict__ mb2,
                float* __restrict__ out)
{
    const int b = blockIdx.x;
    const int t = threadIdx.x;
    const int wave = t >> 6;
    const int lane = t & 63;
    const int lr = lane & 15;
    const int lq = lane >> 4;

    __shared__ f16 sWh[2][8192];   // hi/lo planes: Wh1T -> h1 -> Wh2T   (32 KB)
    __shared__ f16 sPW[8192];      // union: W2 staging (16 KB) / P (8 KB)
    __shared__ float sU[192];
    __shared__ float sSi[64], sSj[64], sInv[64];
    __shared__ float sMmax;
    __shared__ float sPoolW[4][128];   // aliases score partials sCpart[4][2][64] during C
    __shared__ float sPool[128];
    __shared__ float sHid[32];
    __shared__ float sRaw[128];
    __shared__ float sSums[2];

    // ---- Phase A ----
    if (t < 192) sU[t] = users[b * 192 + t];
    __syncthreads();

    // ---- Phase B: Wh1 = users @ W1, store hi/lo WhT[feat][node] ----
    {
        const int f = t >> 1, ih = t & 1;
        const float w0 = W1[f], w1 = W1[128 + f], w2 = W1[256 + f];
        #pragma unroll
        for (int ii = 0; ii < 32; ++ii) {
            const int i = ih * 32 + ii;
            const float v = fmaf(sU[i * 3], w0, fmaf(sU[i * 3 + 1], w1, sU[i * 3 + 2] * w2));
            const f16 hi = (f16)v;
            const f16 lo = (f16)(v - (float)hi);
            const int off = idxWh(f, i);
            sWh[0][off] = hi;
            sWh[1][off] = lo;
        }
    }
    __syncthreads();

    for (int L = 0; L < 2; ++L) {
        if (L == 1) {
            // ---- Phase F: Wh2 = h1 @ W2.  A = h1 (hi/lo, LDS), B = w2t (f16, staged) ----
            __syncthreads();   // h1 stores (end of E, L0) visible
            const int row = wave * 16 + lr;
            f16x8 ahi[4], alo[4];
            #pragma unroll
            for (int ks = 0; ks < 4; ++ks) {
                const int off = row * 128 + ((((ks * 4 + lq) ^ (row & 15))) << 3);
                ahi[ks] = *(const f16x8*)&sWh[0][off];
                alo[ks] = *(const f16x8*)&sWh[1][off];
            }
            f32x4 acc[8];
            #pragma unroll
            for (int nt = 0; nt < 8; ++nt) acc[nt] = (f32x4){0.f, 0.f, 0.f, 0.f};

            for (int half = 0; half < 2; ++half) {
                __syncthreads();   // drains A-frag reads (half 0) / protects sPW reuse (half 1)
                {   // stage 64 rows of w2t into sPW (16 KB), swizzled
                    const int n = t >> 2, c = t & 3;
                    #pragma unroll
                    for (int g4 = 0; g4 < 4; ++g4) {
                        const int g = c * 4 + g4;
                        f16x8 w = *(const f16x8*)(w2t + (half * 64 + n) * 128 + g * 8);
                        *(f16x8*)&sPW[n * 128 + (((g ^ (n & 15))) << 3)] = w;
                    }
                }
                __syncthreads();
                #pragma unroll
                for (int ntl = 0; ntl < 4; ++ntl) {
                    const int nt = half * 4 + ntl;
                    const int nl = ntl * 16 + lr;
                    #pragma unroll
                    for (int ks = 0; ks < 4; ++ks) {
                        const int off = nl * 128 + ((((ks * 4 + lq) ^ (nl & 15))) << 3);
                        f16x8 bf = *(const f16x8*)&sPW[off];
                        acc[nt] = __builtin_amdgcn_mfma_f32_16x16x32_f16(ahi[ks], bf, acc[nt], 0, 0, 0);
                        acc[nt] = __builtin_amdgcn_mfma_f32_16x16x32_f16(alo[ks], bf, acc[nt], 0, 0, 0);
                    }
                }
            }
            // store Wh2T hi/lo: D row = node = wave*16+lq*4+r, col = feat = nt*16+lr
            #pragma unroll
            for (int nt = 0; nt < 8; ++nt) {
                const int feat = nt * 16 + lr;
                const int g = wave * 2 + (lq >> 1);
                const int base = feat * 64 + (((g ^ (feat & 7))) << 3) + ((lq & 1) * 4);
                f16x4 hv, lv;
                #pragma unroll
                for (int r = 0; r < 4; ++r) {
                    const float v = acc[nt][r];
                    const f16 hi = (f16)v;
                    hv[r] = hi;
                    lv[r] = (f16)(v - (float)hi);
                }
                *(f16x4*)&sWh[0][base] = hv;
                *(f16x4*)&sWh[1][base] = lv;
            }
            __syncthreads();
        }

        // ---- Phase C: scores si = Wh@a[:128], sj = Wh@a[128:], all 256 threads ----
        {
            float* sCpart = &sPoolW[0][0];   // [4][2][64]
            const int i = t & 63, q = t >> 6;
            const float* av = (L == 0) ? a1 : a2;
            float s0 = 0.0f, s1 = 0.0f;
            #pragma unroll 8
            for (int kk = 0; kk < 32; ++kk) {
                const int k = q * 32 + kk;
                const int off = idxWh(k, i);
                const float x = (float)sWh[0][off] + (float)sWh[1][off];
                s0 = fmaf(x, av[k], s0);
                s1 = fmaf(x, av[128 + k], s1);
            }
            sCpart[(q * 2 + 0) * 64 + i] = s0;
            sCpart[(q * 2 + 1) * 64 + i] = s1;
        }
        __syncthreads();
        if (t < 128) {
            const float* sCpart = &sPoolW[0][0];
            const int i = t & 63, h = t >> 6;
            const float s = sCpart[(0 * 2 + h) * 64 + i] + sCpart[(1 * 2 + h) * 64 + i]
                          + sCpart[(2 * 2 + h) * 64 + i] + sCpart[(3 * 2 + h) * 64 + i];
            if (h == 0) sSi[i] = s; else sSj[i] = s;
        }
        __syncthreads();
        if (t < 64) {
            float mj = sSj[t];
            #pragma unroll
            for (int off = 1; off < 64; off <<= 1) mj = fmaxf(mj, __shfl_xor(mj, off, 64));
            if (t == 0) sMmax = mj;
        }
        __syncthreads();

        // ---- Phase D: P (unnormalized, f16) + denominator from ROUNDED p ----
        {
            const int i = t >> 2, jq = t & 3;
            const float si = sSi[i];
            const float mi = lrelu(si + sMmax);   // lrelu monotone => row max
            float lsum = 0.0f;
            #pragma unroll
            for (int jj = 0; jj < 16; ++jj) {
                const int j = jq * 16 + jj;
                const float p = __expf(lrelu(si + sSj[j]) - mi);
                const f16 ph = (f16)p;
                lsum += (float)ph;
                sPW[idxP(i, j)] = ph;
            }
            lsum += __shfl_xor(lsum, 1, 64);
            lsum += __shfl_xor(lsum, 2, 64);
            if (jq == 0) sInv[i] = 1.0f / lsum;
        }
        __syncthreads();

        // ---- Phase E: h = elu(diag(inv) * P @ Wh).  A = P (f16), B = WhT (hi/lo) ----
        {
            const int row = wave * 16 + lr;
            f16x8 ap[2];
            #pragma unroll
            for (int ks = 0; ks < 2; ++ks)
                ap[ks] = *(const f16x8*)&sPW[row * 64 + ((((ks * 4 + lq) ^ (row & 7))) << 3)];
            f32x4 acc[8];
            #pragma unroll
            for (int nt = 0; nt < 8; ++nt) acc[nt] = (f32x4){0.f, 0.f, 0.f, 0.f};
            #pragma unroll
            for (int nt = 0; nt < 8; ++nt) {
                const int feat = nt * 16 + lr;
                #pragma unroll
                for (int ks = 0; ks < 2; ++ks) {
                    const int off = feat * 64 + ((((ks * 4 + lq) ^ (feat & 7))) << 3);
                    f16x8 bh = *(const f16x8*)&sWh[0][off];
                    f16x8 bl = *(const f16x8*)&sWh[1][off];
                    acc[nt] = __builtin_amdgcn_mfma_f32_16x16x32_f16(ap[ks], bh, acc[nt], 0, 0, 0);
                    acc[nt] = __builtin_amdgcn_mfma_f32_16x16x32_f16(ap[ks], bl, acc[nt], 0, 0, 0);
                }
            }
            float invr[4];
            #pragma unroll
            for (int r = 0; r < 4; ++r) invr[r] = sInv[wave * 16 + lq * 4 + r];

            if (L == 0) {
                __syncthreads();   // all Wh1T reads done -> safe to overwrite with h1
                #pragma unroll
                for (int nt = 0; nt < 8; ++nt) {
                    const int feat = nt * 16 + lr;
                    #pragma unroll
                    for (int r = 0; r < 4; ++r) {
                        const int node = wave * 16 + lq * 4 + r;
                        const float v = elu1(acc[nt][r] * invr[r]);
                        const f16 hi = (f16)v;
                        const int off = idxH(node, feat);
                        sWh[0][off] = hi;
                        sWh[1][off] = (f16)(v - (float)hi);
                    }
                }
                // visibility barrier = first __syncthreads in Phase F
            } else {
                // pooling from registers: pooled[feat] = elu(max_node h2pre)
                #pragma unroll
                for (int nt = 0; nt < 8; ++nt) {
                    float mx = -1e30f;
                    #pragma unroll
                    for (int r = 0; r < 4; ++r) mx = fmaxf(mx, acc[nt][r] * invr[r]);
                    mx = fmaxf(mx, __shfl_xor(mx, 16, 64));
                    mx = fmaxf(mx, __shfl_xor(mx, 32, 64));
                    if (lq == 0) sPoolW[wave][nt * 16 + lr] = mx;
                }
                __syncthreads();
                if (t < 128)
                    sPool[t] = elu1(fmaxf(fmaxf(sPoolW[0][t], sPoolW[1][t]),
                                          fmaxf(sPoolW[2][t], sPoolW[3][t])));
                __syncthreads();
            }
        }
    }

    // ---- Readout MLP (fp32) ----
    if (t < 32) {
        float s = mb1[t];
        #pragma unroll 8
        for (int c = 0; c < 128; ++c) s = fmaf(sPool[c], mw1[c * 32 + t], s);
        sHid[t] = fmaxf(s, 0.0f);
    }
    __syncthreads();
    if (t < 128) {
        float s = mb2[t];
        #pragma unroll 8
        for (int q = 0; q < 32; ++q) s = fmaf(sHid[q], mw2[q * 128 + t], s);
        sRaw[t] = fmaxf(s, 0.0f) + 1e-6f;
    }
    __syncthreads();
    if (t < 128) {
        float v = sRaw[t];
        #pragma unroll
        for (int off = 32; off > 0; off >>= 1) v += __shfl_down(v, off, 64);
        if ((t & 63) == 0) sSums[t >> 6] = v;
    }
    __syncthreads();
    if (t < 64) {
        const float sumD = sSums[0] + 1e-6f;
        const float sumP = sSums[1] + 1e-6f;
        out[b * 64 + t] = sRaw[64 + t] / sumP;                     // power  (PMAX = 1)
        out[NBATCH * 64 + b * 64 + t] = 98.425f * sRaw[t] / sumD;  // delta  (Bmax = 98.425)
    }
}

extern "C" void kernel_launch(void* const* d_in, const int* in_sizes, int n_in,
                              void* d_out, int out_size, void* d_ws, size_t ws_size,
                              hipStream_t stream) {
    const float* users = (const float*)d_in[0];
    const float* W1    = (const float*)d_in[1];
    const float* a1    = (const float*)d_in[2];
    const float* W2    = (const float*)d_in[3];
    const float* a2    = (const float*)d_in[4];
    const float* mw1   = (const float*)d_in[5];
    const float* mb1   = (const float*)d_in[6];
    const float* mw2   = (const float*)d_in[7];
    const float* mb2   = (const float*)d_in[8];
    float* out = (float*)d_out;
    f16* w2t = (f16*)d_ws;

    w2t_prep<<<64, 256, 0, stream>>>(W2, w2t);
    gat_kernel<<<NBATCH, 256, 0, stream>>>(users, W1, a1, a2, w2t,
                                           mw1, mb1, mw2, mb2, out);
}